// Round 1
// baseline (380.381 us; speedup 1.0000x reference)
//
#include <hip/hip_runtime.h>

#define VOCAB   50000
#define EMBED   128
#define NTOT    200000
#define BATCH   1024
#define NTILE   64
#define NBLK    (NTOT / NTILE)    // 3125
#define MCHUNK  64
#define NCHUNK  (BATCH / MCHUNK)  // 16

typedef __attribute__((ext_vector_type(8))) __bf16 bf16x8;
typedef __attribute__((ext_vector_type(4))) float f32x4;

__device__ __forceinline__ unsigned short f2bf(float f) {
  unsigned int u = __float_as_uint(f);
  u += 0x7FFFu + ((u >> 16) & 1u);   // RNE; inputs are normal floats
  return (unsigned short)(u >> 16);
}

// Kernel 0: h[b][e] = bf16(relu(W1[e][idx[b]]))
__global__ void build_h_kernel(const int* __restrict__ idx,
                               const float* __restrict__ W1,
                               unsigned short* __restrict__ h) {
  int g = blockIdx.x * 256 + threadIdx.x;   // 512 blocks x 256 = 1024*128
  int b = g >> 7, e = g & 127;
  float v = W1[(size_t)e * VOCAB + idx[b]];
  v = fmaxf(v, 0.0f);
  h[g] = f2bf(v);
}

// GEMM pass. PASS==1: per-row sum of exp(logit) -> partial[m][nb].
// PASS==2: out[m][n] = lse[m] - logit[m][n].
template <int PASS>
__global__ __launch_bounds__(256, 4)
void gemm_pass_kernel(const float* __restrict__ W2,
                      const unsigned short* __restrict__ hg,
                      float* __restrict__ partial,
                      const float* __restrict__ lse,
                      float* __restrict__ out) {
  __shared__ __align__(16) char wt[NTILE * 256];   // W2 tile, bf16, swizzled
  __shared__ __align__(16) char ht[MCHUNK * 256];  // h chunk, bf16, swizzled
  __shared__ float rsum[MCHUNK];
  __shared__ float lse_s[MCHUNK];

  const int t    = threadIdx.x;
  const int nb   = blockIdx.x;
  const int n0   = nb * NTILE;
  const int lane = t & 63;
  const int wid  = t >> 6;
  const int wm   = wid >> 1, wn = wid & 1;   // 2x2 wave grid over 64x64 tile

  // Stage W2 tile once: 64 rows x 128 f32 -> bf16, XOR-swizzle 16B units
  #pragma unroll
  for (int i = 0; i < 8; ++i) {
    int u = t + 256 * i;                 // float4 unit, 2048 total
    int r = u >> 5, p = u & 31;
    const float4 v = *(const float4*)(W2 + (size_t)(n0 + r) * EMBED + p * 4);
    unsigned int lo = (unsigned int)f2bf(v.x) | ((unsigned int)f2bf(v.y) << 16);
    unsigned int hi = (unsigned int)f2bf(v.z) | ((unsigned int)f2bf(v.w) << 16);
    int byte = r * 256 + ((p * 8) ^ ((r & 7) << 4));
    *(uint2*)(wt + byte) = make_uint2(lo, hi);
  }

  const int kg = lane >> 4;      // 0..3  (k group)
  const int rl = lane & 15;      // row/col within fragment
  const int rg = kg << 2;        // C/D row base: row=(lane>>4)*4+j

  for (int c = 0; c < NCHUNK; ++c) {
    const int m0 = c * MCHUNK;
    __syncthreads();             // prev chunk fully consumed (also covers wt stage)

    // Stage h chunk: 64 rows x 256 B, straight bf16 copy, swizzled
    #pragma unroll
    for (int i = 0; i < 4; ++i) {
      int u = t + 256 * i;               // 16B units, 1024 total
      int r = u >> 4, p = u & 15;
      uint4 v = *(const uint4*)(hg + (size_t)(m0 + r) * EMBED + p * 8);
      int byte = r * 256 + ((p * 16) ^ ((r & 7) << 4));
      *(uint4*)(ht + byte) = v;
    }
    if (PASS == 1) { if (t < MCHUNK) rsum[t] = 0.0f; }
    else           { if (t < MCHUNK) lse_s[t] = lse[m0 + t]; }
    __syncthreads();

    f32x4 acc[2][2];
    #pragma unroll
    for (int a = 0; a < 2; ++a)
      #pragma unroll
      for (int b = 0; b < 2; ++b)
        acc[a][b] = (f32x4){0.f, 0.f, 0.f, 0.f};

    #pragma unroll
    for (int kk = 0; kk < 4; ++kk) {
      const int kb = kk * 64 + kg * 16;  // byte offset along K
      bf16x8 a0, a1, b0, b1;
      { int r = wm * 32 + rl;      a0 = *(const bf16x8*)(ht + r * 256 + (kb ^ ((r & 7) << 4))); }
      { int r = wm * 32 + 16 + rl; a1 = *(const bf16x8*)(ht + r * 256 + (kb ^ ((r & 7) << 4))); }
      { int r = wn * 32 + rl;      b0 = *(const bf16x8*)(wt + r * 256 + (kb ^ ((r & 7) << 4))); }
      { int r = wn * 32 + 16 + rl; b1 = *(const bf16x8*)(wt + r * 256 + (kb ^ ((r & 7) << 4))); }
      acc[0][0] = __builtin_amdgcn_mfma_f32_16x16x32_bf16(a0, b0, acc[0][0], 0, 0, 0);
      acc[0][1] = __builtin_amdgcn_mfma_f32_16x16x32_bf16(a0, b1, acc[0][1], 0, 0, 0);
      acc[1][0] = __builtin_amdgcn_mfma_f32_16x16x32_bf16(a1, b0, acc[1][0], 0, 0, 0);
      acc[1][1] = __builtin_amdgcn_mfma_f32_16x16x32_bf16(a1, b1, acc[1][1], 0, 0, 0);
    }

    if (PASS == 1) {
      #pragma unroll
      for (int fm = 0; fm < 2; ++fm) {
        float s0 = __expf(acc[fm][0][0]) + __expf(acc[fm][1][0]);
        float s1 = __expf(acc[fm][0][1]) + __expf(acc[fm][1][1]);
        float s2 = __expf(acc[fm][0][2]) + __expf(acc[fm][1][2]);
        float s3 = __expf(acc[fm][0][3]) + __expf(acc[fm][1][3]);
        #pragma unroll
        for (int mask = 1; mask < 16; mask <<= 1) {
          s0 += __shfl_xor(s0, mask);
          s1 += __shfl_xor(s1, mask);
          s2 += __shfl_xor(s2, mask);
          s3 += __shfl_xor(s3, mask);
        }
        if (rl == 0) {
          int rb = wm * 32 + fm * 16 + rg;
          atomicAdd(&rsum[rb + 0], s0);
          atomicAdd(&rsum[rb + 1], s1);
          atomicAdd(&rsum[rb + 2], s2);
          atomicAdd(&rsum[rb + 3], s3);
        }
      }
      __syncthreads();
      if (t < MCHUNK) partial[(size_t)(m0 + t) * NBLK + nb] = rsum[t];
    } else {
      #pragma unroll
      for (int fm = 0; fm < 2; ++fm)
        #pragma unroll
        for (int fn = 0; fn < 2; ++fn)
          #pragma unroll
          for (int j = 0; j < 4; ++j) {
            int rlo = wm * 32 + fm * 16 + rg + j;
            int cg  = n0 + wn * 32 + fn * 16 + rl;
            out[(size_t)(m0 + rlo) * NTOT + cg] = lse_s[rlo] - acc[fm][fn][j];
          }
    }
  }
}

// lse[m] = log( sum_nb partial[m][nb] )
__global__ void reduce_lse_kernel(const float* __restrict__ partial,
                                  float* __restrict__ lse) {
  __shared__ float sb[256];
  int m = blockIdx.x;
  float s = 0.f;
  for (int i = threadIdx.x; i < NBLK; i += 256)
    s += partial[(size_t)m * NBLK + i];
  sb[threadIdx.x] = s;
  __syncthreads();
  for (int k = 128; k > 0; k >>= 1) {
    if (threadIdx.x < k) sb[threadIdx.x] += sb[threadIdx.x + k];
    __syncthreads();
  }
  if (threadIdx.x == 0) lse[m] = logf(sb[0]);
}

extern "C" void kernel_launch(void* const* d_in, const int* in_sizes, int n_in,
                              void* d_out, int out_size, void* d_ws, size_t ws_size,
                              hipStream_t stream) {
  const int*   idx = (const int*)d_in[0];
  const float* W1  = (const float*)d_in[1];
  const float* W2  = (const float*)d_in[2];
  float* out = (float*)d_out;

  // Scratch: partials live in d_out (12.8 MB of its 819 MB; consumed by
  // reduce_lse before pass 2 overwrites every element). ws holds only
  // h (256 KB bf16) + lse (4 KB).
  float* partial = out;
  unsigned short* h = (unsigned short*)d_ws;
  float* lse = (float*)((char*)d_ws + (size_t)BATCH * EMBED * 2);

  build_h_kernel<<<(BATCH * EMBED) / 256, 256, 0, stream>>>(idx, W1, h);
  gemm_pass_kernel<1><<<NBLK, 256, 0, stream>>>(W2, h, partial, nullptr, nullptr);
  reduce_lse_kernel<<<BATCH, 256, 0, stream>>>(partial, lse);
  gemm_pass_kernel<2><<<NBLK, 256, 0, stream>>>(W2, h, partial, lse, out);
}